// Round 10
// baseline (163.437 us; speedup 1.0000x reference)
//
#include <hip/hip_runtime.h>

#define SEQ 32768
#define QSCALE 0.08838834764831845f
#define NCH 16   // chunks per strip (strips=32, 64-row chunks)

typedef __attribute__((ext_vector_type(8))) short short8;
typedef __attribute__((ext_vector_type(8))) __bf16 bf16x8;
typedef __attribute__((ext_vector_type(16))) float f32x16;
typedef __attribute__((ext_vector_type(4))) float f32x4;
typedef __attribute__((ext_vector_type(4))) int int4v;
typedef __attribute__((ext_vector_type(2))) int int2v;

// [R][128]-short tile swizzle: XOR short-idx bits 3..5 with row&7 (16B-unit preserving)
#define SWZ(r, c) ((((r) << 7) + (c)) ^ (((r) & 7) << 3))

__device__ __forceinline__ int cvtpk(float lo, float hi) {
  int r;
  asm("v_cvt_pk_bf16_f32 %0, %1, %2" : "=v"(r) : "v"(lo), "v"(hi));
  return r;
}

__device__ __forceinline__ f32x16 mfma_ii(int4v a, int4v b, f32x16 c) {
  return __builtin_amdgcn_mfma_f32_32x32x16_bf16(
      __builtin_bit_cast(bf16x8, a), __builtin_bit_cast(bf16x8, b), c, 0, 0, 0);
}

// C-layout (reg r <-> n=(r&3)+8*(r>>2)+4*hi, lane) -> A/B frag (reg j <-> n=hi*8+j)
__device__ __forceinline__ int4v build_frag(float e0, float e1, float e2, float e3,
                                            float e4, float e5, float e6, float e7,
                                            int hi) {
  int t0 = cvtpk(e0, e1), t1 = cvtpk(e2, e3);
  int t2 = cvtpk(e4, e5), t3 = cvtpk(e6, e7);
  const int u0 = __shfl_xor(t2, 32), u1 = __shfl_xor(t3, 32);
  const int u2 = __shfl_xor(t0, 32), u3 = __shfl_xor(t1, 32);
  int4v f;
  f[0] = hi ? u0 : t0;
  f[1] = hi ? u1 : t1;
  f[2] = hi ? t2 : u2;
  f[3] = hi ? t3 : u3;
  return f;
}

// ---------------------------------------------------------------------------
// Prep: W fragment table. Wf[side(q,k,v)][tile4][ks8][lane64] = 16B A/B-frag:
// elem j = W[ks*16+(lane>>5)*8+j][side*128 + tile*32 + (lane&31)]  (bf16)
// ---------------------------------------------------------------------------
__global__ void la_prep(const float* __restrict__ Wqkv, int4v* __restrict__ Wf) {
  const int fid = blockIdx.x * 256 + threadIdx.x;  // 6144 frags
  if (fid >= 6144) return;
  const int side = fid >> 11;
  const int rem = fid & 2047;
  const int tile = rem >> 9;
  const int ks = (rem >> 6) & 7;
  const int lane = rem & 63;
  const int k0 = ks * 16 + ((lane >> 5) << 3);
  const int col = side * 128 + tile * 32 + (lane & 31);
  int4v f;
  #pragma unroll
  for (int a = 0; a < 4; ++a)
    f[a] = cvtpk(Wqkv[(k0 + 2 * a) * 384 + col], Wqkv[(k0 + 2 * a + 1) * 384 + col]);
  Wf[fid] = f;
}

// ---------------------------------------------------------------------------
// Pass 1: 16 waves x 64-row chunks; ONE barrier/chunk (r9-proven protocol).
// NEW (r10): 2-chunk-ahead load pipeline — loads for chunk i+2 issue at iter
// i; the registers staged at iter i were loaded at iter i-1 (a full chunk
// of latency slack) -> stage's vmcnt wait ~0.
// grid 256 = 8 batches x 32 strips (1 block/CU); 1024 thr.
// ---------------------------------------------------------------------------
__global__ __launch_bounds__(1024, 4)
void la_pass1(const float* __restrict__ x, const int4v* __restrict__ Wf,
              float* __restrict__ partials) {
  __shared__ __align__(16) short xs[2][64 * 128];       // 32 KB dbuf
  __shared__ int4v fragbuf[2][2][4][4][64];             // 64 KB [buf][side][tile][ks4][lane]
  __shared__ __align__(16) float sumbuf[2][2][2][32][4];// 4 KB [buf][side][rh][n][tile]

  const int tid = threadIdx.x;
  const int lane = tid & 63;
  const int wv = tid >> 6;          // 0..15
  const int l31 = lane & 31;
  const int hi = lane >> 5;
  const int koff = hi << 3;
  const int h = wv >> 3;            // 0=q side, 1=k side
  const int c = (wv >> 1) & 3;      // proj ch-tile
  const int rh = wv & 1;            // row half
  const int td = wv >> 2;           // ctx d-tile
  const int te = wv & 3;            // ctx e-tile
  const float qs = h ? 1.0f : QSCALE;
  const int b = blockIdx.x >> 5;
  const int strip = blockIdx.x & 31;
  const long base = (long)b * SEQ + (long)strip * (NCH * 64);

  // W fragments for this wave's 32-ch tile (coalesced one-time table load)
  int4v wf[8];
  #pragma unroll
  for (int ks = 0; ks < 8; ++ks)
    wf[ks] = Wf[((((h << 2) + c) << 3) + ks) * 64 + lane];

  const int lr = tid >> 4;          // 0..63
  const int cf = (tid & 15) << 3;   // float col
  {  // preload chunk 0 -> xs[0]
    const float* xp = x + (base + lr) * 128 + cf;
    f32x4 u0 = *(const f32x4*)xp;
    f32x4 u1 = *(const f32x4*)(xp + 4);
    int4v p;
    p[0] = cvtpk(u0[0], u0[1]); p[1] = cvtpk(u0[2], u0[3]);
    p[2] = cvtpk(u1[0], u1[1]); p[3] = cvtpk(u1[2], u1[3]);
    *(int4v*)&xs[0][SWZ(lr, cf)] = p;
  }
  // preload chunk 1 -> regs (staged at iter 0)
  f32x4 c0, c1;
  {
    const float* xp = x + (base + 64 + lr) * 128 + cf;
    c0 = *(const f32x4*)xp;
    c1 = *(const f32x4*)(xp + 4);
  }
  __syncthreads();

  f32x16 ctx = {0.f};
  const int r0 = rh << 5;           // this wave's first row in the chunk
  for (int i = 0; i < NCH; ++i) {
    const int cur = i & 1;
    // issue loads for chunk i+2 (consumed NEXT iteration -> full-chunk slack)
    const int inx2 = (i + 2 < NCH) ? i + 2 : NCH - 1;
    const float* xp = x + (base + inx2 * 64 + lr) * 128 + cf;
    f32x4 n0 = *(const f32x4*)xp;
    f32x4 n1 = *(const f32x4*)(xp + 4);

    // o2: P^T (ch in regs, n in lanes) -> row sums (lane-local)
    f32x16 acc = {0.f};
    #pragma unroll
    for (int ks = 0; ks < 8; ++ks) {
      const int4v xf = *(const int4v*)&xs[cur][SWZ(r0 + l31, (ks << 4) + koff)];
      acc = mfma_ii(wf[ks], xf, acc);
    }
    {
      float sa = 0.f, sb = 0.f;
      #pragma unroll
      for (int r = 0; r < 16; r += 2) { sa += __expf(acc[r]); sb += __expf(acc[r + 1]); }
      float s = sa + sb;
      s += __shfl_xor(s, 32);
      if (!hi) sumbuf[cur][h][rh][l31][c] = s;
    }

    // o1: P (n in regs, ch in lanes), exp in place (reuse acc regs)
    acc = f32x16{0.f};
    #pragma unroll
    for (int ks = 0; ks < 8; ++ks) {
      const int4v xf = *(const int4v*)&xs[cur][SWZ(r0 + l31, (ks << 4) + koff)];
      acc = mfma_ii(xf, wf[ks], acc);
    }
    #pragma unroll
    for (int r = 0; r < 16; ++r) acc[r] = __expf(acc[r]);

    {  // stage chunk i+1 (loaded LAST iteration -> vmcnt wait ~0)
      int4v p;
      p[0] = cvtpk(c0[0], c0[1]); p[1] = cvtpk(c0[2], c0[3]);
      p[2] = cvtpk(c1[0], c1[1]); p[3] = cvtpk(c1[2], c1[3]);
      *(int4v*)&xs[cur ^ 1][SWZ(lr, cf)] = p;
    }
    __syncthreads();                    // the ONLY barrier per chunk

    // per-side normalization: q *= QSCALE/sq_n ; k *= 1/sk_n
    #pragma unroll
    for (int r = 0; r < 16; ++r) {
      const int n = (r & 3) + ((r >> 2) << 3) + (hi << 2);
      const f32x4 sv = *(const f32x4*)&sumbuf[cur][h][rh][n][0];
      acc[r] *= qs * __builtin_amdgcn_rcpf(sv[0] + sv[1] + sv[2] + sv[3]);
    }
    fragbuf[cur][h][c][(rh << 1) + 0][lane] =
        build_frag(acc[0], acc[1], acc[2], acc[3], acc[4], acc[5], acc[6], acc[7], hi);
    fragbuf[cur][h][c][(rh << 1) + 1][lane] =
        build_frag(acc[8], acc[9], acc[10], acc[11], acc[12], acc[13], acc[14], acc[15], hi);

    // ctx on PREVIOUS chunk's frags (written post-B_{i-1}; B_i passed since)
    if (i > 0) {
      const int pb = cur ^ 1;
      #pragma unroll
      for (int ks = 0; ks < 4; ++ks)
        ctx = mfma_ii(fragbuf[pb][0][td][ks][lane], fragbuf[pb][1][te][ks][lane], ctx);
    }

    c0 = n0; c1 = n1;   // advance the load pipeline
  }
  __syncthreads();   // final: chunk NCH-1 frag writes visible
  {
    const int pb = (NCH - 1) & 1;
    #pragma unroll
    for (int ks = 0; ks < 4; ++ks)
      ctx = mfma_ii(fragbuf[pb][0][td][ks][lane], fragbuf[pb][1][te][ks][lane], ctx);
  }

  float* pout = partials + (long)blockIdx.x * 16384;
  #pragma unroll
  for (int r = 0; r < 16; ++r) {
    const int drow = (td << 5) + (r & 3) + ((r >> 2) << 3) + (hi << 2);
    pout[(drow << 7) + (te << 5) + l31] = ctx[r];
  }
}

// ---------------------------------------------------------------------------
// Reduce partials -> ctx[b]   (grid 128 = 8 batches x 16 slices)
// ---------------------------------------------------------------------------
__global__ void la_reduce(const float* __restrict__ partials, float* __restrict__ ctx,
                          int strips) {
  const int b = blockIdx.x >> 4;
  const int sl = blockIdx.x & 15;
  const int idx = (sl << 10) + ((int)threadIdx.x << 2);
  f32x4 acc = {0.f};
  for (int st = 0; st < strips; ++st)
    acc += *(const f32x4*)(partials + ((long)(b * strips + st) << 14) + idx);
  *(f32x4*)(ctx + ((long)b << 14) + idx) = acc;
}

// ---------------------------------------------------------------------------
// Mt = (ctx^T W_out)^T stored as interleaved-column MFMA B-frag table:
// Mtf[b][j4][ks8][lane] 16B: elem m = Mt[4*(lane&31)+j][ks*16+(lane>>5)*8+m]
// ---------------------------------------------------------------------------
__global__ void la_mkern(const float* __restrict__ ctx, const float* __restrict__ Wout,
                         int4v* __restrict__ Mtf) {
  __shared__ __align__(16) float cl[128 * 132];
  __shared__ float wo[128 * 32];
  const int tid = threadIdx.x;
  const int b = blockIdx.x >> 2;
  const int d0 = (blockIdx.x & 3) << 5;
  const float* cp = ctx + ((long)b << 14);
  for (int i = tid << 2; i < 16384; i += 1024) {
    f32x4 v = *(const f32x4*)(cp + i);
    *(f32x4*)&cl[(i >> 7) * 132 + (i & 127)] = v;
  }
  for (int i = tid; i < 128 * 32; i += 256)
    wo[i] = Wout[((i >> 5) << 7) + d0 + (i & 31)];
  __syncthreads();
  const int dq = tid >> 3;            // d' within [0,32)
  const int e0 = (tid & 7) << 4;
  float acc[16];
  #pragma unroll
  for (int i = 0; i < 16; ++i) acc[i] = 0.0f;
  for (int d = 0; d < 128; ++d) {
    const float w = wo[(d << 5) + dq];
    const float* cr = &cl[d * 132 + e0];
    #pragma unroll
    for (int i = 0; i < 16; ++i) acc[i] += cr[i] * w;
  }
  const int dp = d0 + dq;             // global d'
  const int j = dp & 3, l = dp >> 2, ks = e0 >> 4;
  int4v lo, hi2;
  lo[0] = cvtpk(acc[0], acc[1]);   lo[1] = cvtpk(acc[2], acc[3]);
  lo[2] = cvtpk(acc[4], acc[5]);   lo[3] = cvtpk(acc[6], acc[7]);
  hi2[0] = cvtpk(acc[8], acc[9]);  hi2[1] = cvtpk(acc[10], acc[11]);
  hi2[2] = cvtpk(acc[12], acc[13]); hi2[3] = cvtpk(acc[14], acc[15]);
  int4v* dst = Mtf + ((((long)b << 2) + j) * 8 + ks) * 64;
  dst[l] = lo;
  dst[32 + l] = hi2;
}

// ---------------------------------------------------------------------------
// Pass 2: BARRIER-FREE, wave-independent (r9-proven compute path).
// NEW (r10): two-burst staging (8+8 loads, lower reg spike) + bounds(256,4)
// for 4 waves/SIMD occupancy.
// ---------------------------------------------------------------------------
__global__ __launch_bounds__(256, 4)
void la_pass2(const float* __restrict__ x, const int4v* __restrict__ Wf,
              const int4v* __restrict__ Mtf, const float* __restrict__ bout,
              float* __restrict__ out) {
  __shared__ __align__(16) short xs[4][32 * 128];   // 8 KB per wave

  const int tid = threadIdx.x;
  const int lane = tid & 63;
  const int wv = tid >> 6;
  const int l31 = lane & 31;
  const int hi = lane >> 5;
  const int koff = hi << 3;
  const int b = blockIdx.x >> 8;
  const int chunk = blockIdx.x & 255;
  const long row0 = (long)b * SEQ + (long)chunk * 128 + (wv << 5);

  {  // two-burst stage: 8 loads, 8 loads, convert+write, convert+write
    const float* xb = x + row0 * 128;
    f32x4 uA[8], uB[8];
    #pragma unroll
    for (int t = 0; t < 8; ++t)
      uA[t] = *(const f32x4*)(xb + t * 256 + lane * 4);
    #pragma unroll
    for (int t = 0; t < 8; ++t)
      uB[t] = *(const f32x4*)(xb + (t + 8) * 256 + lane * 4);
    #pragma unroll
    for (int t = 0; t < 8; ++t) {
      const int flat = t * 256 + lane * 4;
      int2v w;
      w[0] = cvtpk(uA[t][0], uA[t][1]);
      w[1] = cvtpk(uA[t][2], uA[t][3]);
      *(int2v*)&xs[wv][SWZ(flat >> 7, flat & 127)] = w;
    }
    #pragma unroll
    for (int t = 0; t < 8; ++t) {
      const int flat = (t + 8) * 256 + lane * 4;
      int2v w;
      w[0] = cvtpk(uB[t][0], uB[t][1]);
      w[1] = cvtpk(uB[t][2], uB[t][3]);
      *(int2v*)&xs[wv][SWZ(flat >> 7, flat & 127)] = w;
    }
  }
  const f32x4 bias = *(const f32x4*)(bout + (l31 << 2));   // d' = 4*l31+j
  asm volatile("s_waitcnt lgkmcnt(0)" ::: "memory");       // wave-local LDS drain
  __builtin_amdgcn_sched_barrier(0);

  // x fragments for this wave's 32 rows
  int4v xfr[8];
  #pragma unroll
  for (int ks = 0; ks < 8; ++ks)
    xfr[ks] = *(const int4v*)&xs[wv][SWZ(l31, (ks << 4) + koff)];

  // v-proj o2: C[ch in regs][n=l31], 4 ch-tiles; W-frags from L2 table
  const int4v* WvT = Wf + 2 * 2048;   // side 2 (v)
  f32x16 a0 = {0.f}, a1 = {0.f}, a2 = {0.f}, a3 = {0.f};
  #pragma unroll
  for (int ks = 0; ks < 8; ++ks) {
    a0 = mfma_ii(WvT[(0 * 8 + ks) * 64 + lane], xfr[ks], a0);
    a1 = mfma_ii(WvT[(1 * 8 + ks) * 64 + lane], xfr[ks], a1);
    a2 = mfma_ii(WvT[(2 * 8 + ks) * 64 + lane], xfr[ks], a2);
    a3 = mfma_ii(WvT[(3 * 8 + ks) * 64 + lane], xfr[ks], a3);
  }

  // softmax: fully lane-local sum over 128 channels, normalize in f32
  float s = 0.f;
  #pragma unroll
  for (int r = 0; r < 16; ++r) {
    a0[r] = __expf(a0[r]); s += a0[r];
    a1[r] = __expf(a1[r]); s += a1[r];
    a2[r] = __expf(a2[r]); s += a2[r];
    a3[r] = __expf(a3[r]); s += a3[r];
  }
  s += __shfl_xor(s, 32);
  const float inv = __builtin_amdgcn_rcpf(s);
  #pragma unroll
  for (int r = 0; r < 16; ++r) {
    a0[r] *= inv; a1[r] *= inv; a2[r] *= inv; a3[r] *= inv;
  }

  // A-frags for out-GEMM (K = e)
  int4v vf[8];
  vf[0] = build_frag(a0[0], a0[1], a0[2], a0[3], a0[4], a0[5], a0[6], a0[7], hi);
  vf[1] = build_frag(a0[8], a0[9], a0[10], a0[11], a0[12], a0[13], a0[14], a0[15], hi);
  vf[2] = build_frag(a1[0], a1[1], a1[2], a1[3], a1[4], a1[5], a1[6], a1[7], hi);
  vf[3] = build_frag(a1[8], a1[9], a1[10], a1[11], a1[12], a1[13], a1[14], a1[15], hi);
  vf[4] = build_frag(a2[0], a2[1], a2[2], a2[3], a2[4], a2[5], a2[6], a2[7], hi);
  vf[5] = build_frag(a2[8], a2[9], a2[10], a2[11], a2[12], a2[13], a2[14], a2[15], hi);
  vf[6] = build_frag(a3[0], a3[1], a3[2], a3[3], a3[4], a3[5], a3[6], a3[7], hi);
  vf[7] = build_frag(a3[8], a3[9], a3[10], a3[11], a3[12], a3[13], a3[14], a3[15], hi);

  // out[n][d'] = v @ Mt^T + bias ; interleaved Mt B-frags (col c <-> d'=4c+j)
  const int4v* MtB = Mtf + ((long)b << 11);
  f32x16 o0 = {0.f}, o1 = {0.f}, o2 = {0.f}, o3 = {0.f};
  #pragma unroll
  for (int ks = 0; ks < 8; ++ks) {
    o0 = mfma_ii(vf[ks], MtB[(0 * 8 + ks) * 64 + lane], o0);
    o1 = mfma_ii(vf[ks], MtB[(1 * 8 + ks) * 64 + lane], o1);
    o2 = mfma_ii(vf[ks], MtB[(2 * 8 + ks) * 64 + lane], o2);
    o3 = mfma_ii(vf[ks], MtB[(3 * 8 + ks) * 64 + lane], o3);
  }

  float* obase = out + row0 * 128 + (l31 << 2);
  #pragma unroll
  for (int r = 0; r < 16; ++r) {
    const int n = (r & 3) + ((r >> 2) << 3) + (hi << 2);
    f32x4 v;
    v[0] = o0[r] + bias[0];
    v[1] = o1[r] + bias[1];
    v[2] = o2[r] + bias[2];
    v[3] = o3[r] + bias[3];
    *(f32x4*)(obase + (long)n * 128) = v;
  }
}

extern "C" void kernel_launch(void* const* d_in, const int* in_sizes, int n_in,
                              void* d_out, int out_size, void* d_ws, size_t ws_size,
                              hipStream_t stream) {
  const float* x = (const float*)d_in[0];
  const float* Wqkv = (const float*)d_in[1];
  const float* Wout = (const float*)d_in[2];
  const float* bout = (const float*)d_in[3];
  float* out = (float*)d_out;

  const int strips = 32;                 // 256 blocks = 1/CU; 16 MB partials

  float* partials = (float*)d_ws;                        // 8*32 * 16384 f32 = 16 MB
  float* ctx = partials + (size_t)8 * strips * 16384;    // 8 * 16384 f32
  int4v* Mtf = (int4v*)(ctx + 8 * 16384);                // 16384 int4v (256 KB)
  int4v* Wf = Mtf + 16384;                               // 6144 int4v (96 KB)

  la_prep<<<dim3(24), dim3(256), 0, stream>>>(Wqkv, Wf);
  la_pass1<<<dim3(8 * strips), dim3(1024), 0, stream>>>(x, Wf, partials);
  la_reduce<<<dim3(128), dim3(256), 0, stream>>>(partials, ctx, strips);
  la_mkern<<<dim3(32), dim3(256), 0, stream>>>(ctx, Wout, Mtf);
  la_pass2<<<dim3(2048), dim3(256), 0, stream>>>(x, Wf, Mtf, bout, out);
}

// Round 11
// 152.812 us; speedup vs baseline: 1.0695x; 1.0695x over previous
//
#include <hip/hip_runtime.h>

#define SEQ 32768
#define QSCALE 0.08838834764831845f
#define NCH 16   // 64-row chunks per strip (strips=32)

typedef __attribute__((ext_vector_type(8))) short short8;
typedef __attribute__((ext_vector_type(8))) __bf16 bf16x8;
typedef __attribute__((ext_vector_type(16))) float f32x16;
typedef __attribute__((ext_vector_type(4))) float f32x4;
typedef __attribute__((ext_vector_type(4))) int int4v;
typedef __attribute__((ext_vector_type(2))) int int2v;

// [R][128]-short tile swizzle: XOR short-idx bits 3..5 with row&7 (16B-unit preserving)
#define SWZ(r, c) ((((r) << 7) + (c)) ^ (((r) & 7) << 3))
// [128ch][64n]-short value tile: short idx = ch*64 + n, XOR bits 3..5 with ch&7
#define PSWZ(ch, n) ((((ch) << 6) + (n)) ^ (((ch) & 7) << 3))

__device__ __forceinline__ int cvtpk(float lo, float hi) {
  int r;
  asm("v_cvt_pk_bf16_f32 %0, %1, %2" : "=v"(r) : "v"(lo), "v"(hi));
  return r;
}

__device__ __forceinline__ short bf16b(float f) {
  unsigned u = __builtin_bit_cast(unsigned, f);
  u += 0x7fffu + ((u >> 16) & 1u);   // RNE
  return (short)(u >> 16);
}

__device__ __forceinline__ f32x16 mfma_ii(int4v a, int4v b, f32x16 c) {
  return __builtin_amdgcn_mfma_f32_32x32x16_bf16(
      __builtin_bit_cast(bf16x8, a), __builtin_bit_cast(bf16x8, b), c, 0, 0, 0);
}

// C-layout (reg r <-> n=(r&3)+8*(r>>2)+4*hi, lane) -> A/B frag (reg j <-> n=hi*8+j)
__device__ __forceinline__ int4v build_frag(float e0, float e1, float e2, float e3,
                                            float e4, float e5, float e6, float e7,
                                            int hi) {
  int t0 = cvtpk(e0, e1), t1 = cvtpk(e2, e3);
  int t2 = cvtpk(e4, e5), t3 = cvtpk(e6, e7);
  const int u0 = __shfl_xor(t2, 32), u1 = __shfl_xor(t3, 32);
  const int u2 = __shfl_xor(t0, 32), u3 = __shfl_xor(t1, 32);
  int4v f;
  f[0] = hi ? u0 : t0;
  f[1] = hi ? u1 : t1;
  f[2] = hi ? t2 : u2;
  f[3] = hi ? t3 : u3;
  return f;
}

// ---------------------------------------------------------------------------
// Prep: W fragment table. Wf[side(q,k,v)][tile4][ks8][lane64] = 16B A/B-frag:
// elem j = W[ks*16+(lane>>5)*8+j][side*128 + tile*32 + (lane&31)]  (bf16)
// ---------------------------------------------------------------------------
__global__ void la_prep(const float* __restrict__ Wqkv, int4v* __restrict__ Wf) {
  const int fid = blockIdx.x * 256 + threadIdx.x;  // 6144 frags
  if (fid >= 6144) return;
  const int side = fid >> 11;
  const int rem = fid & 2047;
  const int tile = rem >> 9;
  const int ks = (rem >> 6) & 7;
  const int lane = rem & 63;
  const int k0 = ks * 16 + ((lane >> 5) << 3);
  const int col = side * 128 + tile * 32 + (lane & 31);
  int4v f;
  #pragma unroll
  for (int a = 0; a < 4; ++a)
    f[a] = cvtpk(Wqkv[(k0 + 2 * a) * 384 + col], Wqkv[(k0 + 2 * a + 1) * 384 + col]);
  Wf[fid] = f;
}

// ---------------------------------------------------------------------------
// Pass 1 (r11): SINGLE projection per tile (o2 only). o2 layout (lane = n)
// makes softmax norm a per-lane scalar (1 rcp, no shfl); normalized values go
// through a swizzled LDS transpose tile ptile[side][ch][n] (ds_write_b16),
// and ctx reads A/B frags as natural b128 rows. MFMA/wave/chunk 20->12,
// no o1, no build_frag. Sync protocol = r9-proven (1 barrier, trailing ctx).
// grid 256 = 8 batches x 32 strips; 1024 thr (16 waves).
// ---------------------------------------------------------------------------
__global__ __launch_bounds__(1024, 4)
void la_pass1(const float* __restrict__ x, const int4v* __restrict__ Wf,
              float* __restrict__ partials) {
  __shared__ __align__(16) short xs[2][64 * 128];        // 32 KB dbuf
  __shared__ __align__(16) short ptile[2][2][128 * 64];  // 64 KB [buf][side][ch][n]
  __shared__ __align__(16) float sumbuf[2][2][2][32][4]; // 4 KB [buf][side][rh][n][tile]

  const int tid = threadIdx.x;
  const int lane = tid & 63;
  const int wv = tid >> 6;          // 0..15
  const int l31 = lane & 31;
  const int hi = lane >> 5;
  const int koff = hi << 3;
  const int h = wv >> 3;            // 0=q side, 1=k side
  const int c = (wv >> 1) & 3;      // proj ch-tile
  const int rh = wv & 1;            // row half
  const int td = wv >> 2;           // ctx d-tile
  const int te = wv & 3;            // ctx e-tile
  const float qs = h ? 1.0f : QSCALE;
  const int b = blockIdx.x >> 5;
  const int strip = blockIdx.x & 31;
  const long base = (long)b * SEQ + (long)strip * (NCH * 64);

  // W fragments for this wave's 32-ch tile (coalesced one-time table load)
  int4v wf[8];
  #pragma unroll
  for (int ks = 0; ks < 8; ++ks)
    wf[ks] = Wf[((((h << 2) + c) << 3) + ks) * 64 + lane];

  const int lr = tid >> 4;          // 0..63
  const int cf = (tid & 15) << 3;   // float col
  {  // preload chunk 0 -> xs[0]
    const float* xp = x + (base + lr) * 128 + cf;
    f32x4 u0 = *(const f32x4*)xp;
    f32x4 u1 = *(const f32x4*)(xp + 4);
    int4v p;
    p[0] = cvtpk(u0[0], u0[1]); p[1] = cvtpk(u0[2], u0[3]);
    p[2] = cvtpk(u1[0], u1[1]); p[3] = cvtpk(u1[2], u1[3]);
    *(int4v*)&xs[0][SWZ(lr, cf)] = p;
  }
  __syncthreads();

  f32x16 ctx = {0.f};
  const int r0 = rh << 5;           // this wave's first row in the chunk
  for (int i = 0; i < NCH; ++i) {
    const int cur = i & 1;
    const int inx = (i + 1 < NCH) ? i + 1 : i;
    const float* xp = x + (base + inx * 64 + lr) * 128 + cf;
    f32x4 u0 = *(const f32x4*)xp;
    f32x4 u1 = *(const f32x4*)(xp + 4);

    // o2: P^T (ch in regs, n in lanes); exp in place -> values AND sums
    f32x16 acc = {0.f};
    #pragma unroll
    for (int ks = 0; ks < 8; ++ks) {
      const int4v xf = *(const int4v*)&xs[cur][SWZ(r0 + l31, (ks << 4) + koff)];
      acc = mfma_ii(wf[ks], xf, acc);
    }
    {
      float sa = 0.f, sb = 0.f;
      #pragma unroll
      for (int r = 0; r < 16; r += 2) {
        acc[r] = __expf(acc[r]);     sa += acc[r];
        acc[r + 1] = __expf(acc[r + 1]); sb += acc[r + 1];
      }
      float s = sa + sb;
      s += __shfl_xor(s, 32);       // lanes n and n+32 hold complementary ch-halves
      if (!hi) sumbuf[cur][h][rh][l31][c] = s;
    }

    {  // stage next chunk (re-write of read buffer is 1 barrier away)
      int4v p;
      p[0] = cvtpk(u0[0], u0[1]); p[1] = cvtpk(u0[2], u0[3]);
      p[2] = cvtpk(u1[0], u1[1]); p[3] = cvtpk(u1[2], u1[3]);
      *(int4v*)&xs[cur ^ 1][SWZ(lr, cf)] = p;
    }
    __syncthreads();                    // the ONLY barrier per chunk

    // norm: per-lane scalar (lane = n) -> write transposed value tile
    {
      const f32x4 sv = *(const f32x4*)&sumbuf[cur][h][rh][l31][0];
      const float invn = qs * __builtin_amdgcn_rcpf(sv[0] + sv[1] + sv[2] + sv[3]);
      short* pt = &ptile[cur][h][0];
      const int n = (rh << 5) + l31;
      #pragma unroll
      for (int r = 0; r < 16; ++r) {
        const int ch = (c << 5) + (r & 3) + ((r >> 2) << 3) + (hi << 2);
        pt[PSWZ(ch, n)] = bf16b(acc[r] * invn);
      }
    }

    // trailing ctx on PREVIOUS chunk's tiles (B_i separates write/read)
    if (i > 0) {
      const int pb = cur ^ 1;
      #pragma unroll
      for (int ks = 0; ks < 4; ++ks) {
        const int4v aq = *(const int4v*)&ptile[pb][0][PSWZ((td << 5) + l31, (ks << 4) + koff)];
        const int4v bk = *(const int4v*)&ptile[pb][1][PSWZ((te << 5) + l31, (ks << 4) + koff)];
        ctx = mfma_ii(aq, bk, ctx);
      }
    }
  }
  __syncthreads();   // final: chunk NCH-1 tile writes visible
  {
    const int pb = (NCH - 1) & 1;
    #pragma unroll
    for (int ks = 0; ks < 4; ++ks) {
      const int4v aq = *(const int4v*)&ptile[pb][0][PSWZ((td << 5) + l31, (ks << 4) + koff)];
      const int4v bk = *(const int4v*)&ptile[pb][1][PSWZ((te << 5) + l31, (ks << 4) + koff)];
      ctx = mfma_ii(aq, bk, ctx);
    }
  }

  float* pout = partials + (long)blockIdx.x * 16384;
  #pragma unroll
  for (int r = 0; r < 16; ++r) {
    const int drow = (td << 5) + (r & 3) + ((r >> 2) << 3) + (hi << 2);
    pout[(drow << 7) + (te << 5) + l31] = ctx[r];
  }
}

// ---------------------------------------------------------------------------
// Reduce partials -> ctx[b]   (grid 128 = 8 batches x 16 slices)
// ---------------------------------------------------------------------------
__global__ void la_reduce(const float* __restrict__ partials, float* __restrict__ ctx,
                          int strips) {
  const int b = blockIdx.x >> 4;
  const int sl = blockIdx.x & 15;
  const int idx = (sl << 10) + ((int)threadIdx.x << 2);
  f32x4 acc = {0.f};
  for (int st = 0; st < strips; ++st)
    acc += *(const f32x4*)(partials + ((long)(b * strips + st) << 14) + idx);
  *(f32x4*)(ctx + ((long)b << 14) + idx) = acc;
}

// ---------------------------------------------------------------------------
// Mt = (ctx^T W_out)^T stored as interleaved-column MFMA B-frag table:
// Mtf[b][j4][ks8][lane] 16B: elem m = Mt[4*(lane&31)+j][ks*16+(lane>>5)*8+m]
// ---------------------------------------------------------------------------
__global__ void la_mkern(const float* __restrict__ ctx, const float* __restrict__ Wout,
                         int4v* __restrict__ Mtf) {
  __shared__ __align__(16) float cl[128 * 132];
  __shared__ float wo[128 * 32];
  const int tid = threadIdx.x;
  const int b = blockIdx.x >> 2;
  const int d0 = (blockIdx.x & 3) << 5;
  const float* cp = ctx + ((long)b << 14);
  for (int i = tid << 2; i < 16384; i += 1024) {
    f32x4 v = *(const f32x4*)(cp + i);
    *(f32x4*)&cl[(i >> 7) * 132 + (i & 127)] = v;
  }
  for (int i = tid; i < 128 * 32; i += 256)
    wo[i] = Wout[((i >> 5) << 7) + d0 + (i & 31)];
  __syncthreads();
  const int dq = tid >> 3;            // d' within [0,32)
  const int e0 = (tid & 7) << 4;
  float acc[16];
  #pragma unroll
  for (int i = 0; i < 16; ++i) acc[i] = 0.0f;
  for (int d = 0; d < 128; ++d) {
    const float w = wo[(d << 5) + dq];
    const float* cr = &cl[d * 132 + e0];
    #pragma unroll
    for (int i = 0; i < 16; ++i) acc[i] += cr[i] * w;
  }
  const int dp = d0 + dq;             // global d'
  const int j = dp & 3, l = dp >> 2, ks = e0 >> 4;
  int4v lo, hi2;
  lo[0] = cvtpk(acc[0], acc[1]);   lo[1] = cvtpk(acc[2], acc[3]);
  lo[2] = cvtpk(acc[4], acc[5]);   lo[3] = cvtpk(acc[6], acc[7]);
  hi2[0] = cvtpk(acc[8], acc[9]);  hi2[1] = cvtpk(acc[10], acc[11]);
  hi2[2] = cvtpk(acc[12], acc[13]); hi2[3] = cvtpk(acc[14], acc[15]);
  int4v* dst = Mtf + ((((long)b << 2) + j) * 8 + ks) * 64;
  dst[l] = lo;
  dst[32 + l] = hi2;
}

// ---------------------------------------------------------------------------
// Pass 2: BARRIER-FREE, wave-independent (r9-proven, exact revert).
// ---------------------------------------------------------------------------
__global__ __launch_bounds__(256, 3)
void la_pass2(const float* __restrict__ x, const int4v* __restrict__ Wf,
              const int4v* __restrict__ Mtf, const float* __restrict__ bout,
              float* __restrict__ out) {
  __shared__ __align__(16) short xs[4][32 * 128];   // 8 KB per wave

  const int tid = threadIdx.x;
  const int lane = tid & 63;
  const int wv = tid >> 6;
  const int l31 = lane & 31;
  const int hi = lane >> 5;
  const int koff = hi << 3;
  const int b = blockIdx.x >> 8;
  const int chunk = blockIdx.x & 255;
  const long row0 = (long)b * SEQ + (long)chunk * 128 + (wv << 5);

  {  // two-phase stage: all loads issued, then convert+write
    const float* xb = x + row0 * 128;
    f32x4 u[16];
    #pragma unroll
    for (int t = 0; t < 16; ++t)
      u[t] = *(const f32x4*)(xb + t * 256 + lane * 4);
    #pragma unroll
    for (int t = 0; t < 16; ++t) {
      const int flat = t * 256 + lane * 4;   // f32 index within 32x128
      int2v w;
      w[0] = cvtpk(u[t][0], u[t][1]);
      w[1] = cvtpk(u[t][2], u[t][3]);
      *(int2v*)&xs[wv][SWZ(flat >> 7, flat & 127)] = w;
    }
  }
  const f32x4 bias = *(const f32x4*)(bout + (l31 << 2));   // d' = 4*l31+j
  asm volatile("s_waitcnt lgkmcnt(0)" ::: "memory");       // wave-local LDS drain
  __builtin_amdgcn_sched_barrier(0);

  // x fragments for this wave's 32 rows
  int4v xfr[8];
  #pragma unroll
  for (int ks = 0; ks < 8; ++ks)
    xfr[ks] = *(const int4v*)&xs[wv][SWZ(l31, (ks << 4) + koff)];

  // v-proj o2: C[ch in regs][n=l31], 4 ch-tiles; W-frags from L2 table
  const int4v* WvT = Wf + 2 * 2048;   // side 2 (v)
  f32x16 a0 = {0.f}, a1 = {0.f}, a2 = {0.f}, a3 = {0.f};
  #pragma unroll
  for (int ks = 0; ks < 8; ++ks) {
    a0 = mfma_ii(WvT[(0 * 8 + ks) * 64 + lane], xfr[ks], a0);
    a1 = mfma_ii(WvT[(1 * 8 + ks) * 64 + lane], xfr[ks], a1);
    a2 = mfma_ii(WvT[(2 * 8 + ks) * 64 + lane], xfr[ks], a2);
    a3 = mfma_ii(WvT[(3 * 8 + ks) * 64 + lane], xfr[ks], a3);
  }

  // softmax: fully lane-local sum over 128 channels, normalize in f32
  float s = 0.f;
  #pragma unroll
  for (int r = 0; r < 16; ++r) {
    a0[r] = __expf(a0[r]); s += a0[r];
    a1[r] = __expf(a1[r]); s += a1[r];
    a2[r] = __expf(a2[r]); s += a2[r];
    a3[r] = __expf(a3[r]); s += a3[r];
  }
  s += __shfl_xor(s, 32);
  const float inv = __builtin_amdgcn_rcpf(s);
  #pragma unroll
  for (int r = 0; r < 16; ++r) {
    a0[r] *= inv; a1[r] *= inv; a2[r] *= inv; a3[r] *= inv;
  }

  // A-frags for out-GEMM (K = e)
  int4v vf[8];
  vf[0] = build_frag(a0[0], a0[1], a0[2], a0[3], a0[4], a0[5], a0[6], a0[7], hi);
  vf[1] = build_frag(a0[8], a0[9], a0[10], a0[11], a0[12], a0[13], a0[14], a0[15], hi);
  vf[2] = build_frag(a1[0], a1[1], a1[2], a1[3], a1[4], a1[5], a1[6], a1[7], hi);
  vf[3] = build_frag(a1[8], a1[9], a1[10], a1[11], a1[12], a1[13], a1[14], a1[15], hi);
  vf[4] = build_frag(a2[0], a2[1], a2[2], a2[3], a2[4], a2[5], a2[6], a2[7], hi);
  vf[5] = build_frag(a2[8], a2[9], a2[10], a2[11], a2[12], a2[13], a2[14], a2[15], hi);
  vf[6] = build_frag(a3[0], a3[1], a3[2], a3[3], a3[4], a3[5], a3[6], a3[7], hi);
  vf[7] = build_frag(a3[8], a3[9], a3[10], a3[11], a3[12], a3[13], a3[14], a3[15], hi);

  // out[n][d'] = v @ Mt^T + bias ; interleaved Mt B-frags (col c <-> d'=4c+j)
  const int4v* MtB = Mtf + ((long)b << 11);
  f32x16 o0 = {0.f}, o1 = {0.f}, o2 = {0.f}, o3 = {0.f};
  #pragma unroll
  for (int ks = 0; ks < 8; ++ks) {
    o0 = mfma_ii(vf[ks], MtB[(0 * 8 + ks) * 64 + lane], o0);
    o1 = mfma_ii(vf[ks], MtB[(1 * 8 + ks) * 64 + lane], o1);
    o2 = mfma_ii(vf[ks], MtB[(2 * 8 + ks) * 64 + lane], o2);
    o3 = mfma_ii(vf[ks], MtB[(3 * 8 + ks) * 64 + lane], o3);
  }

  float* obase = out + row0 * 128 + (l31 << 2);
  #pragma unroll
  for (int r = 0; r < 16; ++r) {
    const int n = (r & 3) + ((r >> 2) << 3) + (hi << 2);
    f32x4 v;
    v[0] = o0[r] + bias[0];
    v[1] = o1[r] + bias[1];
    v[2] = o2[r] + bias[2];
    v[3] = o3[r] + bias[3];
    *(f32x4*)(obase + (long)n * 128) = v;
  }
}

extern "C" void kernel_launch(void* const* d_in, const int* in_sizes, int n_in,
                              void* d_out, int out_size, void* d_ws, size_t ws_size,
                              hipStream_t stream) {
  const float* x = (const float*)d_in[0];
  const float* Wqkv = (const float*)d_in[1];
  const float* Wout = (const float*)d_in[2];
  const float* bout = (const float*)d_in[3];
  float* out = (float*)d_out;

  const int strips = 32;                 // 256 blocks = 1/CU; 16 MB partials

  float* partials = (float*)d_ws;                        // 8*32 * 16384 f32 = 16 MB
  float* ctx = partials + (size_t)8 * strips * 16384;    // 8 * 16384 f32
  int4v* Mtf = (int4v*)(ctx + 8 * 16384);                // 16384 int4v (256 KB)
  int4v* Wf = Mtf + 16384;                               // 6144 int4v (96 KB)

  la_prep<<<dim3(24), dim3(256), 0, stream>>>(Wqkv, Wf);
  la_pass1<<<dim3(8 * strips), dim3(1024), 0, stream>>>(x, Wf, partials);
  la_reduce<<<dim3(128), dim3(256), 0, stream>>>(partials, ctx, strips);
  la_mkern<<<dim3(32), dim3(256), 0, stream>>>(ctx, Wout, Mtf);
  la_pass2<<<dim3(2048), dim3(256), 0, stream>>>(x, Wf, Mtf, bout, out);
}

// Round 12
// 149.306 us; speedup vs baseline: 1.0946x; 1.0235x over previous
//
#include <hip/hip_runtime.h>

#define SEQ 32768
#define QSCALE 0.08838834764831845f
#define NCH 16   // 64-row chunks per strip (strips=32)

typedef __attribute__((ext_vector_type(8))) short short8;
typedef __attribute__((ext_vector_type(8))) __bf16 bf16x8;
typedef __attribute__((ext_vector_type(16))) float f32x16;
typedef __attribute__((ext_vector_type(4))) float f32x4;
typedef __attribute__((ext_vector_type(4))) int int4v;
typedef __attribute__((ext_vector_type(2))) int int2v;

// [R][128]-short tile swizzle: XOR short-idx bits 3..6 with row&15 — all 16
// 16B slots used -> 32-lane b128 column reads are 2-way (free) not 4-way
#define SWZ(r, c) ((((r) << 7) + (c)) ^ (((r) & 15) << 3))
// [128ch][64n]-short value tile: 8 slots only (col space 64 shorts)
#define PSWZ(ch, n) ((((ch) << 6) + (n)) ^ (((ch) & 7) << 3))

__device__ __forceinline__ int cvtpk(float lo, float hi) {
  int r;
  asm("v_cvt_pk_bf16_f32 %0, %1, %2" : "=v"(r) : "v"(lo), "v"(hi));
  return r;
}

__device__ __forceinline__ short bf16b(float f) {
  unsigned u = __builtin_bit_cast(unsigned, f);
  u += 0x7fffu + ((u >> 16) & 1u);   // RNE
  return (short)(u >> 16);
}

__device__ __forceinline__ f32x16 mfma_ii(int4v a, int4v b, f32x16 c) {
  return __builtin_amdgcn_mfma_f32_32x32x16_bf16(
      __builtin_bit_cast(bf16x8, a), __builtin_bit_cast(bf16x8, b), c, 0, 0, 0);
}

// C-layout (reg r <-> n=(r&3)+8*(r>>2)+4*hi, lane) -> A/B frag (reg j <-> n=hi*8+j)
__device__ __forceinline__ int4v build_frag(float e0, float e1, float e2, float e3,
                                            float e4, float e5, float e6, float e7,
                                            int hi) {
  int t0 = cvtpk(e0, e1), t1 = cvtpk(e2, e3);
  int t2 = cvtpk(e4, e5), t3 = cvtpk(e6, e7);
  const int u0 = __shfl_xor(t2, 32), u1 = __shfl_xor(t3, 32);
  const int u2 = __shfl_xor(t0, 32), u3 = __shfl_xor(t1, 32);
  int4v f;
  f[0] = hi ? u0 : t0;
  f[1] = hi ? u1 : t1;
  f[2] = hi ? t2 : u2;
  f[3] = hi ? t3 : u3;
  return f;
}

// ---------------------------------------------------------------------------
// Prep: W fragment table. Wf[side(q,k,v)][tile4][ks8][lane64] = 16B A/B-frag:
// elem j = W[ks*16+(lane>>5)*8+j][side*128 + tile*32 + (lane&31)]  (bf16)
// ---------------------------------------------------------------------------
__global__ void la_prep(const float* __restrict__ Wqkv, int4v* __restrict__ Wf) {
  const int fid = blockIdx.x * 256 + threadIdx.x;  // 6144 frags
  if (fid >= 6144) return;
  const int side = fid >> 11;
  const int rem = fid & 2047;
  const int tile = rem >> 9;
  const int ks = (rem >> 6) & 7;
  const int lane = rem & 63;
  const int k0 = ks * 16 + ((lane >> 5) << 3);
  const int col = side * 128 + tile * 32 + (lane & 31);
  int4v f;
  #pragma unroll
  for (int a = 0; a < 4; ++a)
    f[a] = cvtpk(Wqkv[(k0 + 2 * a) * 384 + col], Wqkv[(k0 + 2 * a + 1) * 384 + col]);
  Wf[fid] = f;
}

// ---------------------------------------------------------------------------
// Pass 1 (r12): r11 structure (single o2 projection, scatter-transpose ptile,
// 1 barrier/chunk, trailing ctx). Deltas: 16-slot SWZ; q-side absorbs ALL
// normalization (k stores raw exp); ctx MFMA issued before norm/scatter.
// grid 256 = 8 batches x 32 strips; 1024 thr (16 waves).
// ---------------------------------------------------------------------------
__global__ __launch_bounds__(1024, 4)
void la_pass1(const float* __restrict__ x, const int4v* __restrict__ Wf,
              float* __restrict__ partials) {
  __shared__ __align__(16) short xs[2][64 * 128];        // 32 KB dbuf
  __shared__ __align__(16) short ptile[2][2][128 * 64];  // 64 KB [buf][side][ch][n]
  __shared__ __align__(16) float sumbuf[2][2][2][32][4]; // 4 KB [buf][side][rh][n][tile]

  const int tid = threadIdx.x;
  const int lane = tid & 63;
  const int wv = tid >> 6;          // 0..15
  const int l31 = lane & 31;
  const int hi = lane >> 5;
  const int koff = hi << 3;
  const int h = wv >> 3;            // 0=q side, 1=k side
  const int c = (wv >> 1) & 3;      // proj ch-tile
  const int rh = wv & 1;            // row half
  const int td = wv >> 2;           // ctx d-tile
  const int te = wv & 3;            // ctx e-tile
  const int b = blockIdx.x >> 5;
  const int strip = blockIdx.x & 31;
  const long base = (long)b * SEQ + (long)strip * (NCH * 64);

  // W fragments for this wave's 32-ch tile (coalesced one-time table load)
  int4v wf[8];
  #pragma unroll
  for (int ks = 0; ks < 8; ++ks)
    wf[ks] = Wf[((((h << 2) + c) << 3) + ks) * 64 + lane];

  const int lr = tid >> 4;          // 0..63
  const int cf = (tid & 15) << 3;   // float col
  {  // preload chunk 0 -> xs[0]
    const float* xp = x + (base + lr) * 128 + cf;
    f32x4 u0 = *(const f32x4*)xp;
    f32x4 u1 = *(const f32x4*)(xp + 4);
    int4v p;
    p[0] = cvtpk(u0[0], u0[1]); p[1] = cvtpk(u0[2], u0[3]);
    p[2] = cvtpk(u1[0], u1[1]); p[3] = cvtpk(u1[2], u1[3]);
    *(int4v*)&xs[0][SWZ(lr, cf)] = p;
  }
  __syncthreads();

  f32x16 ctx = {0.f};
  const int r0 = rh << 5;           // this wave's first row in the chunk
  for (int i = 0; i < NCH; ++i) {
    const int cur = i & 1;
    const int inx = (i + 1 < NCH) ? i + 1 : i;
    const float* xp = x + (base + inx * 64 + lr) * 128 + cf;
    f32x4 u0 = *(const f32x4*)xp;
    f32x4 u1 = *(const f32x4*)(xp + 4);

    // o2: P^T (ch in regs, n in lanes); exp in place -> values AND sums
    f32x16 acc = {0.f};
    #pragma unroll
    for (int ks = 0; ks < 8; ++ks) {
      const int4v xf = *(const int4v*)&xs[cur][SWZ(r0 + l31, (ks << 4) + koff)];
      acc = mfma_ii(wf[ks], xf, acc);
    }
    {
      float sa = 0.f, sb = 0.f;
      #pragma unroll
      for (int r = 0; r < 16; r += 2) {
        acc[r] = __expf(acc[r]);     sa += acc[r];
        acc[r + 1] = __expf(acc[r + 1]); sb += acc[r + 1];
      }
      float s = sa + sb;
      s += __shfl_xor(s, 32);       // lanes n and n+32 hold complementary ch-halves
      if (!hi) sumbuf[cur][h][rh][l31][c] = s;
    }

    {  // stage next chunk (re-write of read buffer is 1 barrier away)
      int4v p;
      p[0] = cvtpk(u0[0], u0[1]); p[1] = cvtpk(u0[2], u0[3]);
      p[2] = cvtpk(u1[0], u1[1]); p[3] = cvtpk(u1[2], u1[3]);
      *(int4v*)&xs[cur ^ 1][SWZ(lr, cf)] = p;
    }
    __syncthreads();                    // the ONLY barrier per chunk

    // trailing ctx on PREVIOUS chunk's tiles FIRST (independent of this
    // chunk's ptile writes; fills the MFMA pipe early)
    if (i > 0) {
      const int pb = cur ^ 1;
      #pragma unroll
      for (int ks = 0; ks < 4; ++ks) {
        const int4v aq = *(const int4v*)&ptile[pb][0][PSWZ((td << 5) + l31, (ks << 4) + koff)];
        const int4v bk = *(const int4v*)&ptile[pb][1][PSWZ((te << 5) + l31, (ks << 4) + koff)];
        ctx = mfma_ii(aq, bk, ctx);
      }
    }

    // norm+transpose write: q absorbs QSCALE/(sq*sk); k stores raw exp
    {
      short* pt = &ptile[cur][h][0];
      const int n = (rh << 5) + l31;
      if (h == 0) {
        const f32x4 sq = *(const f32x4*)&sumbuf[cur][0][rh][l31][0];
        const f32x4 sk = *(const f32x4*)&sumbuf[cur][1][rh][l31][0];
        const float invn = QSCALE * __builtin_amdgcn_rcpf(
            (sq[0] + sq[1] + sq[2] + sq[3]) * (sk[0] + sk[1] + sk[2] + sk[3]));
        #pragma unroll
        for (int r = 0; r < 16; ++r) {
          const int ch = (c << 5) + (r & 3) + ((r >> 2) << 3) + (hi << 2);
          pt[PSWZ(ch, n)] = bf16b(acc[r] * invn);
        }
      } else {
        #pragma unroll
        for (int r = 0; r < 16; ++r) {
          const int ch = (c << 5) + (r & 3) + ((r >> 2) << 3) + (hi << 2);
          pt[PSWZ(ch, n)] = bf16b(acc[r]);
        }
      }
    }
  }
  __syncthreads();   // final: chunk NCH-1 tile writes visible
  {
    const int pb = (NCH - 1) & 1;
    #pragma unroll
    for (int ks = 0; ks < 4; ++ks) {
      const int4v aq = *(const int4v*)&ptile[pb][0][PSWZ((td << 5) + l31, (ks << 4) + koff)];
      const int4v bk = *(const int4v*)&ptile[pb][1][PSWZ((te << 5) + l31, (ks << 4) + koff)];
      ctx = mfma_ii(aq, bk, ctx);
    }
  }

  float* pout = partials + (long)blockIdx.x * 16384;
  #pragma unroll
  for (int r = 0; r < 16; ++r) {
    const int drow = (td << 5) + (r & 3) + ((r >> 2) << 3) + (hi << 2);
    pout[(drow << 7) + (te << 5) + l31] = ctx[r];
  }
}

// ---------------------------------------------------------------------------
// Reduce partials -> ctx[b]   (grid 128 = 8 batches x 16 slices)
// ---------------------------------------------------------------------------
__global__ void la_reduce(const float* __restrict__ partials, float* __restrict__ ctx,
                          int strips) {
  const int b = blockIdx.x >> 4;
  const int sl = blockIdx.x & 15;
  const int idx = (sl << 10) + ((int)threadIdx.x << 2);
  f32x4 acc = {0.f};
  for (int st = 0; st < strips; ++st)
    acc += *(const f32x4*)(partials + ((long)(b * strips + st) << 14) + idx);
  *(f32x4*)(ctx + ((long)b << 14) + idx) = acc;
}

// ---------------------------------------------------------------------------
// Mt = (ctx^T W_out)^T stored as interleaved-column MFMA B-frag table:
// Mtf[b][j4][ks8][lane] 16B: elem m = Mt[4*(lane&31)+j][ks*16+(lane>>5)*8+m]
// ---------------------------------------------------------------------------
__global__ void la_mkern(const float* __restrict__ ctx, const float* __restrict__ Wout,
                         int4v* __restrict__ Mtf) {
  __shared__ __align__(16) float cl[128 * 132];
  __shared__ float wo[128 * 32];
  const int tid = threadIdx.x;
  const int b = blockIdx.x >> 2;
  const int d0 = (blockIdx.x & 3) << 5;
  const float* cp = ctx + ((long)b << 14);
  for (int i = tid << 2; i < 16384; i += 1024) {
    f32x4 v = *(const f32x4*)(cp + i);
    *(f32x4*)&cl[(i >> 7) * 132 + (i & 127)] = v;
  }
  for (int i = tid; i < 128 * 32; i += 256)
    wo[i] = Wout[((i >> 5) << 7) + d0 + (i & 31)];
  __syncthreads();
  const int dq = tid >> 3;            // d' within [0,32)
  const int e0 = (tid & 7) << 4;
  float acc[16];
  #pragma unroll
  for (int i = 0; i < 16; ++i) acc[i] = 0.0f;
  for (int d = 0; d < 128; ++d) {
    const float w = wo[(d << 5) + dq];
    const float* cr = &cl[d * 132 + e0];
    #pragma unroll
    for (int i = 0; i < 16; ++i) acc[i] += cr[i] * w;
  }
  const int dp = d0 + dq;             // global d'
  const int j = dp & 3, l = dp >> 2, ks = e0 >> 4;
  int4v lo, hi2;
  lo[0] = cvtpk(acc[0], acc[1]);   lo[1] = cvtpk(acc[2], acc[3]);
  lo[2] = cvtpk(acc[4], acc[5]);   lo[3] = cvtpk(acc[6], acc[7]);
  hi2[0] = cvtpk(acc[8], acc[9]);  hi2[1] = cvtpk(acc[10], acc[11]);
  hi2[2] = cvtpk(acc[12], acc[13]); hi2[3] = cvtpk(acc[14], acc[15]);
  int4v* dst = Mtf + ((((long)b << 2) + j) * 8 + ks) * 64;
  dst[l] = lo;
  dst[32 + l] = hi2;
}

// ---------------------------------------------------------------------------
// Pass 2: BARRIER-FREE, wave-independent (r11-proven; only SWZ def changed).
// ---------------------------------------------------------------------------
__global__ __launch_bounds__(256, 3)
void la_pass2(const float* __restrict__ x, const int4v* __restrict__ Wf,
              const int4v* __restrict__ Mtf, const float* __restrict__ bout,
              float* __restrict__ out) {
  __shared__ __align__(16) short xs[4][32 * 128];   // 8 KB per wave

  const int tid = threadIdx.x;
  const int lane = tid & 63;
  const int wv = tid >> 6;
  const int l31 = lane & 31;
  const int hi = lane >> 5;
  const int koff = hi << 3;
  const int b = blockIdx.x >> 8;
  const int chunk = blockIdx.x & 255;
  const long row0 = (long)b * SEQ + (long)chunk * 128 + (wv << 5);

  {  // two-phase stage: all loads issued, then convert+write
    const float* xb = x + row0 * 128;
    f32x4 u[16];
    #pragma unroll
    for (int t = 0; t < 16; ++t)
      u[t] = *(const f32x4*)(xb + t * 256 + lane * 4);
    #pragma unroll
    for (int t = 0; t < 16; ++t) {
      const int flat = t * 256 + lane * 4;   // f32 index within 32x128
      int2v w;
      w[0] = cvtpk(u[t][0], u[t][1]);
      w[1] = cvtpk(u[t][2], u[t][3]);
      *(int2v*)&xs[wv][SWZ(flat >> 7, flat & 127)] = w;
    }
  }
  const f32x4 bias = *(const f32x4*)(bout + (l31 << 2));   // d' = 4*l31+j
  asm volatile("s_waitcnt lgkmcnt(0)" ::: "memory");       // wave-local LDS drain
  __builtin_amdgcn_sched_barrier(0);

  // x fragments for this wave's 32 rows
  int4v xfr[8];
  #pragma unroll
  for (int ks = 0; ks < 8; ++ks)
    xfr[ks] = *(const int4v*)&xs[wv][SWZ(l31, (ks << 4) + koff)];

  // v-proj o2: C[ch in regs][n=l31], 4 ch-tiles; W-frags from L2 table
  const int4v* WvT = Wf + 2 * 2048;   // side 2 (v)
  f32x16 a0 = {0.f}, a1 = {0.f}, a2 = {0.f}, a3 = {0.f};
  #pragma unroll
  for (int ks = 0; ks < 8; ++ks) {
    a0 = mfma_ii(WvT[(0 * 8 + ks) * 64 + lane], xfr[ks], a0);
    a1 = mfma_ii(WvT[(1 * 8 + ks) * 64 + lane], xfr[ks], a1);
    a2 = mfma_ii(WvT[(2 * 8 + ks) * 64 + lane], xfr[ks], a2);
    a3 = mfma_ii(WvT[(3 * 8 + ks) * 64 + lane], xfr[ks], a3);
  }

  // softmax: fully lane-local sum over 128 channels, normalize in f32
  float s = 0.f;
  #pragma unroll
  for (int r = 0; r < 16; ++r) {
    a0[r] = __expf(a0[r]); s += a0[r];
    a1[r] = __expf(a1[r]); s += a1[r];
    a2[r] = __expf(a2[r]); s += a2[r];
    a3[r] = __expf(a3[r]); s += a3[r];
  }
  s += __shfl_xor(s, 32);
  const float inv = __builtin_amdgcn_rcpf(s);
  #pragma unroll
  for (int r = 0; r < 16; ++r) {
    a0[r] *= inv; a1[r] *= inv; a2[r] *= inv; a3[r] *= inv;
  }

  // A-frags for out-GEMM (K = e)
  int4v vf[8];
  vf[0] = build_frag(a0[0], a0[1], a0[2], a0[3], a0[4], a0[5], a0[6], a0[7], hi);
  vf[1] = build_frag(a0[8], a0[9], a0[10], a0[11], a0[12], a0[13], a0[14], a0[15], hi);
  vf[2] = build_frag(a1[0], a1[1], a1[2], a1[3], a1[4], a1[5], a1[6], a1[7], hi);
  vf[3] = build_frag(a1[8], a1[9], a1[10], a1[11], a1[12], a1[13], a1[14], a1[15], hi);
  vf[4] = build_frag(a2[0], a2[1], a2[2], a2[3], a2[4], a2[5], a2[6], a2[7], hi);
  vf[5] = build_frag(a2[8], a2[9], a2[10], a2[11], a2[12], a2[13], a2[14], a2[15], hi);
  vf[6] = build_frag(a3[0], a3[1], a3[2], a3[3], a3[4], a3[5], a3[6], a3[7], hi);
  vf[7] = build_frag(a3[8], a3[9], a3[10], a3[11], a3[12], a3[13], a3[14], a3[15], hi);

  // out[n][d'] = v @ Mt^T + bias ; interleaved Mt B-frags (col c <-> d'=4c+j)
  const int4v* MtB = Mtf + ((long)b << 11);
  f32x16 o0 = {0.f}, o1 = {0.f}, o2 = {0.f}, o3 = {0.f};
  #pragma unroll
  for (int ks = 0; ks < 8; ++ks) {
    o0 = mfma_ii(vf[ks], MtB[(0 * 8 + ks) * 64 + lane], o0);
    o1 = mfma_ii(vf[ks], MtB[(1 * 8 + ks) * 64 + lane], o1);
    o2 = mfma_ii(vf[ks], MtB[(2 * 8 + ks) * 64 + lane], o2);
    o3 = mfma_ii(vf[ks], MtB[(3 * 8 + ks) * 64 + lane], o3);
  }

  float* obase = out + row0 * 128 + (l31 << 2);
  #pragma unroll
  for (int r = 0; r < 16; ++r) {
    const int n = (r & 3) + ((r >> 2) << 3) + (hi << 2);
    f32x4 v;
    v[0] = o0[r] + bias[0];
    v[1] = o1[r] + bias[1];
    v[2] = o2[r] + bias[2];
    v[3] = o3[r] + bias[3];
    *(f32x4*)(obase + (long)n * 128) = v;
  }
}

extern "C" void kernel_launch(void* const* d_in, const int* in_sizes, int n_in,
                              void* d_out, int out_size, void* d_ws, size_t ws_size,
                              hipStream_t stream) {
  const float* x = (const float*)d_in[0];
  const float* Wqkv = (const float*)d_in[1];
  const float* Wout = (const float*)d_in[2];
  const float* bout = (const float*)d_in[3];
  float* out = (float*)d_out;

  const int strips = 32;                 // 256 blocks = 1/CU; 16 MB partials

  float* partials = (float*)d_ws;                        // 8*32 * 16384 f32 = 16 MB
  float* ctx = partials + (size_t)8 * strips * 16384;    // 8 * 16384 f32
  int4v* Mtf = (int4v*)(ctx + 8 * 16384);                // 16384 int4v (256 KB)
  int4v* Wf = Mtf + 16384;                               // 6144 int4v (96 KB)

  la_prep<<<dim3(24), dim3(256), 0, stream>>>(Wqkv, Wf);
  la_pass1<<<dim3(8 * strips), dim3(1024), 0, stream>>>(x, Wf, partials);
  la_reduce<<<dim3(128), dim3(256), 0, stream>>>(partials, ctx, strips);
  la_mkern<<<dim3(32), dim3(256), 0, stream>>>(ctx, Wout, Mtf);
  la_pass2<<<dim3(2048), dim3(256), 0, stream>>>(x, Wf, Mtf, bout, out);
}